// Round 19
// baseline (471.482 us; speedup 1.0000x reference)
//
#include <hip/hip_runtime.h>
#include <math.h>

// ---- problem sizes ----
// BS=16, T=48, N=147, IN=294, H=128, AH=8(dh=16), GH=4, DFF=2048, B2=BS*T=768

typedef _Float16 half8 __attribute__((ext_vector_type(8)));
typedef _Float16 half4 __attribute__((ext_vector_type(4)));
typedef _Float16 half2v __attribute__((ext_vector_type(2)));
typedef float f32x4 __attribute__((ext_vector_type(4)));

#if __has_builtin(__builtin_amdgcn_fdot2)
#define DOT2(a,b,c) __builtin_amdgcn_fdot2((a),(b),(c),false)
#else
#define DOT2(a,b,c) ((c) + (float)(a)[0]*(float)(b)[0] + (float)(a)[1]*(float)(b)[1])
#endif

// ---- workspace float offsets ----
static constexpr size_t Y0o   = 0;         //  98304  [768][128] f32
static constexpr size_t QKVo  = 98304;     // 294912  [768][384] f32
static constexpr size_t ATTOo = 393216;    //  98304
static constexpr size_t Y1o   = 491520;    //  98304  f32 (residual for k6b)
static constexpr size_t Y1Ho  = 589824;    //  49152  fp16 [768][128]
static constexpr size_t FFHo  = 638976;    // 786432  fp16 [768][2048]
static constexpr size_t Y2Ho  = 1523712;   //  49152  fp16 [768][128]
static constexpr size_t XW1o  = 1572864;   // 903168  f32 [768][1176]
static constexpr size_t Y3o   = 2476032;   // 225792  f32 [768][294] (ends 2701824)
static constexpr size_t Zo    = 0;         // fp16 [768][18816] = 7225344 floats (aliases phase A)
static constexpr size_t So    = 7225344;   // 903168  [768][4][147][2]
static constexpr size_t WHOTo = 8354304;   // fp16 [768][128][160] = 7864320 floats (ends 16218624)
static constexpr size_t WFo   = 16218624;  // fp16 [512][18816] = 4816896 (ends 21035520)
static constexpr size_t ZGPo  = 21035520;  // f32 [12][768][512] = 4718592 (also k6g partials early)
static constexpr size_t ZGo   = 25754112;  // 393216 [768][512]
static constexpr size_t HTo   = 26147328;  //   2048 [16][128]
static constexpr size_t C12o  = 26149376;  //     16
static constexpr size_t WT1Ho = 26149392;  // fp16 [7 p][37 kg][168 row][8] = 348096 -> 174048 floats
static constexpr size_t WT2Ho = 26323440;  // fp16 [16][512][8]  = 32768
static constexpr size_t FF1Ho = 26356208;  // fp16 [2048][128] = 131072
static constexpr size_t FF2Ho = 26487280;  // fp16 [128][2048] = 131072
static constexpr size_t WIH1Ho= 26618352;  // fp16 [1216][128] = 77824 (rows>=1176 zero)
static constexpr size_t W2To  = 26696176;  // fp16 [128][512] = 32768
static constexpr size_t EINTo = 26728944;  //  49152 [128][384] f32
static constexpr size_t EOUTTo= 26778096;  //  16384 [128][128] f32
static constexpr size_t WTRTo = 26794480;  //  37632 [294][128] f32
static constexpr size_t MASKo = 26832112;  //  u64[441] (896 floats reserved)
static constexpr size_t HXo   = 26833008;  //  u32[2][16][294] = 9408 u32 = 9408 floats
// total extent: 26,842,416 floats = 102.4 MiB

__device__ __forceinline__ float eluf(float x){ return x > 0.f ? x : __expf(x)-1.f; }
__device__ __forceinline__ float sigf(float x){ return 1.f/(1.f+__expf(-x)); }

// ---------- merged: weight transposes / fp16 packs + Wih2 conv + c12/mask/HX ----------
__global__ void k_prep_all(const float* Whh1, const float* Whh2, const float* ff1w,
                           const float* ff2w, const float* Wih1, const float* einw,
                           const float* eoutw, const float* wtr, const float* gw2,
                           const float* Wih2, const float* gw1, const float* ga1,
                           const int* adj, float* ws) {
  int bb = blockIdx.x;
  int tid = threadIdx.x;
  if (bb < 4931) {
    int id = bb * 256 + tid;
    if (id < 348096) { // WT1S fp16 [7 p][37 kg][168 row][8 e]
      int e=id&7, r=id>>3; int row=r%168; int q=r/168; int kg=q%37; int p=q/37;
      int k=kg*8+e; int gate=row/42, jr=row-gate*42; int j=gate*294+p*42+jr;
      ((_Float16*)(ws+WT1Ho))[id] = (_Float16)((k<294)? Whh1[j*294+k] : 0.f); return; }
    id -= 348096;
    if (id < 65536) { // WT2H fp16 [16][512][8]
      int e=id&7, r=id>>3; int j=r&511, gi=r>>9; int k=gi*8+e;
      ((_Float16*)(ws+WT2Ho))[id] = (_Float16)Whh2[j*128+k]; return; }
    id -= 65536;
    if (id < 262144) { ((_Float16*)(ws+FF1Ho))[id] = (_Float16)ff1w[id]; return; }
    id -= 262144;
    if (id < 262144) { ((_Float16*)(ws+FF2Ho))[id] = (_Float16)ff2w[id]; return; }
    id -= 262144;
    if (id < 155648) { int j=id>>7, k=id&127;
      ((_Float16*)(ws+WIH1Ho))[id] = (_Float16)((j<1176)? Wih1[j*128+k] : 0.f); return; }
    id -= 155648;
    if (id < 65536)  { int h=id>>9, q=id&511;
      ((_Float16*)(ws+W2To))[id] = (_Float16)gw2[q*128+h]; return; }
    id -= 65536;
    if (id < 49152)  { int k=id/384,  j=id-k*384;  ws[EINTo+id] = einw[j*128+k]; return; }
    id -= 49152;
    if (id < 16384)  { int k=id/128,  j=id-k*128;  ws[EOUTTo+id]= eoutw[j*128+k]; return; }
    id -= 16384;
    if (id < 37632)  { int k=id/128,  j=id-k*128;  ws[WTRTo+id] = wtr[j*294+k]; return; }
    return;
  }
  if (bb < 14339) { // Wih2 -> fp16
    size_t i = ((size_t)(bb-4931)*256 + tid)*4;
    _Float16* wf = (_Float16*)(ws + WFo);
    float4 v = *(const float4*)&Wih2[i];
    half4 h = {(_Float16)v.x, (_Float16)v.y, (_Float16)v.z, (_Float16)v.w};
    *(half4*)&wf[i] = h;
    return;
  }
  // last block: c12 + adjacency bitmask + HX reset
  if (tid < 8) {
    int k = tid>>1, c = tid&1;
    float a=0.f, b=0.f;
    for (int h=0; h<128; ++h) {
      float w = gw1[(k*2+c)*128+h];
      a += w * ga1[k*256+h];
      b += w * ga1[k*256+128+h];
    }
    ws[C12o+tid] = a; ws[C12o+8+tid] = b;
  }
  unsigned long long* msk = (unsigned long long*)(ws + MASKo);
  for (int i = tid; i < 441; i += 256) {
    int r = i/3, w = i-r*3;
    unsigned long long b = 0ull;
    for (int bit=0; bit<64; ++bit) {
      int j = w*64+bit;
      if (j < 147 && adj[r*147+j] > 0) b |= (1ull<<bit);
    }
    msk[i] = b;
  }
  unsigned* hx = (unsigned*)(ws + HXo);
  for (int i=tid;i<9408;i+=256) hx[i]=0u;
}

// ---------- fused input projection + ELU + QKV ----------
__global__ void k1_qkv(const float* X, const float* btr, const float* einb, float* ws) {
  int row = blockIdx.x, tid = threadIdx.x; // 384 thr
  __shared__ float xr[294];
  __shared__ float yr[128];
  for (int i=tid; i<294; i+=384) xr[i] = X[row*294+i];
  __syncthreads();
  if (tid<128){
    float acc = btr[tid];
    const float* w = ws + WTRTo;
    for (int k=0;k<294;++k) acc += xr[k]*w[k*128+tid];
    float v = eluf(acc);
    yr[tid]=v;
    ws[Y0o + (size_t)row*128 + tid] = v;
  }
  __syncthreads();
  float acc = einb[tid];
  const float* w = ws + EINTo;
  for (int k=0;k<128;++k) acc += yr[k]*w[k*384+tid];
  ws[QKVo + (size_t)row*384 + tid] = acc;
}

// ---------- MHA core: one block per (bs, head, row-half) = 256 blocks ----------
__global__ void k3_attn(float* ws) {
  int bid = blockIdx.x; int bs = bid>>4; int a=(bid>>1)&7; int hf=bid&1; int tid = threadIdx.x; // 256 thr
  __shared__ float q[24][16], kk[48][16], v[48][16], sc[24][49];
  int r0=hf*24;
  for (int idx=tid; idx<768; idx+=256) {
    int t = idx>>4, d = idx&15;
    const float* base = ws + QKVo + (size_t)(bs*48+t)*384 + a*16 + d;
    kk[t][d] = base[128]; v[t][d] = base[256];
  }
  for (int idx=tid; idx<384; idx+=256) {
    int t = idx>>4, d = idx&15;
    q[t][d] = ws[QKVo + (size_t)(bs*48+r0+t)*384 + a*16 + d];
  }
  __syncthreads();
  for (int idx=tid; idx<1152; idx+=256) {
    int i = idx/48, j = idx-i*48;
    float s = 0.f;
    for (int d=0;d<16;++d) s += q[i][d]*kk[j][d];
    sc[i][j] = s*0.25f;
  }
  __syncthreads();
  if (tid < 24) {
    float mx = -INFINITY;
    for (int j=0;j<48;++j) mx = fmaxf(mx, sc[tid][j]);
    float s = 0.f;
    for (int j=0;j<48;++j){ float p = __expf(sc[tid][j]-mx); sc[tid][j]=p; s+=p; }
    float inv = 1.f/s;
    for (int j=0;j<48;++j) sc[tid][j]*=inv;
  }
  __syncthreads();
  for (int idx=tid; idx<384; idx+=256) {
    int t = idx>>4, d = idx&15;
    float s=0.f;
    for (int j=0;j<48;++j) s += sc[t][j]*v[j][d];
    ws[ATTOo + (size_t)(bs*48+r0+t)*128 + a*16 + d] = s;
  }
}

// ---------- attn out-proj + residual + LN1 (stores f32 + fp16) ----------
__global__ void k4_ln1(const float* eoutb, const float* g, const float* b, float* ws) {
  int row = blockIdx.x, tid = threadIdx.x; // 128 thr
  __shared__ float orow[128];
  __shared__ float red[128];
  __shared__ float mv[2];
  orow[tid] = ws[ATTOo+(size_t)row*128+tid];
  __syncthreads();
  float acc = eoutb[tid] + ws[Y0o+(size_t)row*128+tid];
  const float* w = ws + EOUTTo;
  for (int k=0;k<128;++k) acc += orow[k]*w[k*128+tid];
  red[tid]=acc; __syncthreads();
  for (int s=64;s>0;s>>=1){ if(tid<s) red[tid]+=red[tid+s]; __syncthreads(); }
  if (tid==0) mv[0]=red[0]*(1.f/128.f);
  __syncthreads();
  float d = acc - mv[0];
  red[tid]=d*d; __syncthreads();
  for (int s=64;s>0;s>>=1){ if(tid<s) red[tid]+=red[tid+s]; __syncthreads(); }
  if (tid==0) mv[1]=red[0]*(1.f/128.f);
  __syncthreads();
  float val = d*rsqrtf(mv[1]+1e-5f)*g[tid]+b[tid];
  ws[Y1o+(size_t)row*128+tid] = val;
  ((_Float16*)(ws+Y1Ho))[(size_t)row*128+tid] = (_Float16)val;
}

// ---------- FFN1 MFMA (1 wave/block, 384 blocks): FFH = relu(Y1 @ ff1w^T + b1), fp16 out ----------
__global__ void __launch_bounds__(64) k5g(const float* b1, float* ws) {
  int tid=threadIdx.x; int gw=blockIdx.x;
  int l=tid&63, lr=l&15, kg=l>>4;
  int mt=gw>>5, nt=gw&31;
  const _Float16* A=(const _Float16*)(ws+Y1Ho);
  const _Float16* B=(const _Float16*)(ws+FF1Ho);
  _Float16* C=(_Float16*)(ws+FFHo);
  size_t r0=(size_t)mt*64, c0=(size_t)nt*64;
  f32x4 acc[4][4];
  #pragma unroll
  for(int a=0;a<4;++a)
    #pragma unroll
    for(int b=0;b<4;++b) acc[a][b]=(f32x4){0.f,0.f,0.f,0.f};
  #pragma unroll
  for (int s=0;s<4;++s){
    int kb=s*32+kg*8;
    half8 av[4], bv[4];
    #pragma unroll
    for(int f=0;f<4;++f) av[f]=*(const half8*)(A+(r0+f*16+lr)*128+kb);
    #pragma unroll
    for(int f=0;f<4;++f) bv[f]=*(const half8*)(B+(c0+f*16+lr)*128+kb);
    #pragma unroll
    for(int fr=0;fr<4;++fr)
      #pragma unroll
      for(int fc=0;fc<4;++fc)
        acc[fr][fc]=__builtin_amdgcn_mfma_f32_16x16x32_f16(av[fr],bv[fc],acc[fr][fc],0,0,0);
  }
  #pragma unroll
  for(int fr=0;fr<4;++fr)
    #pragma unroll
    for(int fc=0;fc<4;++fc){
      size_t col=c0+fc*16+lr;
      float bb=b1[col];
      #pragma unroll
      for(int r=0;r<4;++r){
        float v=acc[fr][fc][r]+bb; v=fmaxf(v,0.f);
        C[(r0+fr*16+kg*4+r)*2048+col]=(_Float16)v;
      }
    }
}

// ---------- FFN2 MFMA split-K=4 (1 wave/block, 96 blocks): ZGP[ksp] partials ----------
__global__ void __launch_bounds__(64) k6g(float* ws) {
  int tid=threadIdx.x; int gw=blockIdx.x;
  int l=tid&63, lr=l&15, kg=l>>4;
  int ksp=gw&3, nt=(gw>>2)&1, mt=gw>>3;
  const _Float16* A=(const _Float16*)(ws+FFHo);
  const _Float16* B=(const _Float16*)(ws+FF2Ho);
  float* C=ws+ZGPo+(size_t)ksp*98304;
  size_t r0=(size_t)mt*64, c0=(size_t)nt*64;
  f32x4 acc[4][4];
  #pragma unroll
  for(int a=0;a<4;++a)
    #pragma unroll
    for(int b=0;b<4;++b) acc[a][b]=(f32x4){0.f,0.f,0.f,0.f};
  #pragma unroll
  for (int s=0;s<16;++s){
    int kb=ksp*512+s*32+kg*8;
    half8 av[4], bv[4];
    #pragma unroll
    for(int f=0;f<4;++f) av[f]=*(const half8*)(A+(r0+f*16+lr)*2048+kb);
    #pragma unroll
    for(int f=0;f<4;++f) bv[f]=*(const half8*)(B+(c0+f*16+lr)*2048+kb);
    #pragma unroll
    for(int fr=0;fr<4;++fr)
      #pragma unroll
      for(int fc=0;fc<4;++fc)
        acc[fr][fc]=__builtin_amdgcn_mfma_f32_16x16x32_f16(av[fr],bv[fc],acc[fr][fc],0,0,0);
  }
  #pragma unroll
  for(int fr=0;fr<4;++fr)
    #pragma unroll
    for(int fc=0;fc<4;++fc){
      size_t col=c0+fc*16+lr;
      #pragma unroll
      for(int r=0;r<4;++r)
        C[(r0+fr*16+kg*4+r)*128+col]=acc[fr][fc][r];
    }
}

// ---------- LN2: Y2H = LN(Y1 + b2 + sum ZGP partials) fp16 ----------
__global__ void k6b_ln2(const float* b2, const float* g, const float* b, float* ws) {
  int row=blockIdx.x, tid=threadIdx.x; // 128 thr
  __shared__ float red[128];
  __shared__ float mv[2];
  float acc = ws[Y1o+(size_t)row*128+tid] + b2[tid];
  #pragma unroll
  for (int ksp=0;ksp<4;++ksp) acc += ws[ZGPo+(size_t)ksp*98304+(size_t)row*128+tid];
  red[tid]=acc; __syncthreads();
  for (int s=64;s>0;s>>=1){ if(tid<s) red[tid]+=red[tid+s]; __syncthreads(); }
  if (tid==0) mv[0]=red[0]*(1.f/128.f);
  __syncthreads();
  float d = acc - mv[0];
  red[tid]=d*d; __syncthreads();
  for (int s=64;s>0;s>>=1){ if(tid<s) red[tid]+=red[tid+s]; __syncthreads(); }
  if (tid==0) mv[1]=red[0]*(1.f/128.f);
  __syncthreads();
  float val = d*rsqrtf(mv[1]+1e-5f)*g[tid]+b[tid];
  ((_Float16*)(ws+Y2Ho))[(size_t)row*128+tid] = (_Float16)val;
}

// ---------- LSTM1 input proj MFMA (1 wave/block, 228 blocks): XW1 = Y2 @ Wih1^T + biases ----------
__global__ void __launch_bounds__(64) k7g(const float* bih1, const float* bhh1, float* ws) {
  int tid=threadIdx.x; int gw=blockIdx.x;
  int l=tid&63, lr=l&15, kg=l>>4;
  int mt=gw/19, nt=gw-mt*19;
  const _Float16* A=(const _Float16*)(ws+Y2Ho);
  const _Float16* B=(const _Float16*)(ws+WIH1Ho);
  float* C=ws+XW1o;
  size_t r0=(size_t)mt*64, c0=(size_t)nt*64;
  f32x4 acc[4][4];
  #pragma unroll
  for(int a=0;a<4;++a)
    #pragma unroll
    for(int b=0;b<4;++b) acc[a][b]=(f32x4){0.f,0.f,0.f,0.f};
  #pragma unroll
  for (int s=0;s<4;++s){
    int kb=s*32+kg*8;
    half8 av[4], bv[4];
    #pragma unroll
    for(int f=0;f<4;++f) av[f]=*(const half8*)(A+(r0+f*16+lr)*128+kb);
    #pragma unroll
    for(int f=0;f<4;++f) bv[f]=*(const half8*)(B+(c0+f*16+lr)*128+kb);
    #pragma unroll
    for(int fr=0;fr<4;++fr)
      #pragma unroll
      for(int fc=0;fc<4;++fc)
        acc[fr][fc]=__builtin_amdgcn_mfma_f32_16x16x32_f16(av[fr],bv[fc],acc[fr][fc],0,0,0);
  }
  #pragma unroll
  for(int fr=0;fr<4;++fr)
    #pragma unroll
    for(int fc=0;fc<4;++fc){
      size_t col=c0+fc*16+lr;
      if (col<1176){
        float bb=bih1[col]+bhh1[col];
        #pragma unroll
        for(int r=0;r<4;++r)
          C[(r0+fr*16+kg*4+r)*1176+col]=acc[fr][fc][r]+bb;
      }
    }
}

// ---------- LSTM1 recurrence: 7 blocks/batch, LDS weights, u32 seqlock, 4-acc ILP ----------
__global__ void __launch_bounds__(256) k8_lstm1(float* ws) {
  int blk=blockIdx.x; int xcd=blk&7; int slot7=blk>>3;
  int b=xcd+8*(slot7/7), p=slot7%7; int tid=threadIdx.x; // 112 blocks, 256 thr
  __shared__ __align__(16) _Float16 wl[49728];  // [37 kg][168 row][8] = 97KB
  __shared__ __align__(16) _Float16 hls[296];
  __shared__ float gbuf[168];
  __shared__ float cloc[42];
  const half8* wsrc = (const half8*)((const _Float16*)(ws+WT1Ho) + (size_t)p*49728);
  for (int i=tid;i<6216;i+=256) ((half8*)wl)[i]=wsrc[i];
  if (tid<42) cloc[tid]=0.f;
  for (int i=tid;i<296;i+=256) hls[i]=(_Float16)0.f;
  unsigned* HX=(unsigned*)(ws+HXo); // [2][16][294] u32
  int gate=tid/42, jr=tid-gate*42;  // meaningful for tid<168
  int j=(tid<168)? gate*294+p*42+jr : 0;
  float xw = (tid<168)? ws[XW1o+(size_t)(b*48)*1176+j] : 0.f;
  int own_lo=p*42;
  __syncthreads();
  for (int t=0;t<48;++t){
    if (tid<168){
      float a0=xw, a1=0.f, a2=0.f, a3=0.f;
      #pragma unroll
      for (int gi=0;gi<36;gi+=4){
        half8 w0=*(const half8*)&wl[((size_t)gi*168+tid)*8];
        half8 w1=*(const half8*)&wl[((size_t)(gi+1)*168+tid)*8];
        half8 w2=*(const half8*)&wl[((size_t)(gi+2)*168+tid)*8];
        half8 w3=*(const half8*)&wl[((size_t)(gi+3)*168+tid)*8];
        const half2v* h0=(const half2v*)&hls[gi*8];
        const half2v* h1=(const half2v*)&hls[(gi+1)*8];
        const half2v* h2=(const half2v*)&hls[(gi+2)*8];
        const half2v* h3=(const half2v*)&hls[(gi+3)*8];
        #pragma unroll
        for (int q=0;q<4;++q){
          half2v wp0={w0[2*q],w0[2*q+1]}; a0=DOT2(wp0,h0[q],a0);
          half2v wp1={w1[2*q],w1[2*q+1]}; a1=DOT2(wp1,h1[q],a1);
          half2v wp2={w2[2*q],w2[2*q+1]}; a2=DOT2(wp2,h2[q],a2);
          half2v wp3={w3[2*q],w3[2*q+1]}; a3=DOT2(wp3,h3[q],a3);
        }
      }
      {
        half8 w0=*(const half8*)&wl[((size_t)36*168+tid)*8];
        const half2v* h0=(const half2v*)&hls[36*8];
        #pragma unroll
        for (int q=0;q<4;++q){ half2v wp0={w0[2*q],w0[2*q+1]}; a0=DOT2(wp0,h0[q],a0); }
      }
      gbuf[tid]=(a0+a1)+(a2+a3);
    }
    __syncthreads();
    if (tid<42){
      int k=p*42+tid;
      float ii=sigf(gbuf[tid]);
      float ff=sigf(gbuf[42+tid]);
      float gg=tanhf(gbuf[84+tid]);
      float oo=sigf(gbuf[126+tid]);
      float cn=ff*cloc[tid]+ii*gg; cloc[tid]=cn;
      float hn=oo*tanhf(cn);
      _Float16 hh=(_Float16)hn;
      hls[k]=hh;
      if (t<47){
        unsigned short pb; __builtin_memcpy(&pb,&hh,2);
        unsigned v=(((unsigned)(t+1))<<16)|(unsigned)pb;
        __hip_atomic_store(&HX[(unsigned)(((t+1)&1)*4704 + b*294 + k)], v,
                           __ATOMIC_RELAXED, __HIP_MEMORY_SCOPE_AGENT);
      }
      ws[Y3o+(size_t)(b*48+t)*294+k]=hn;
    }
    if (t<47){
      if (tid<168) xw = ws[XW1o+(size_t)(b*48+t+1)*1176+j]; // prefetch hides under poll
      unsigned tag=(unsigned)(t+1);
      unsigned sb=(unsigned)(((t+1)&1)*4704 + b*294);
      if (tid>=42){
        int fi = tid-42;            // foreign index 0..213
        int u0 = (fi<own_lo)? fi : fi+42;
        unsigned v;
        for(;;){
          v=__hip_atomic_load(&HX[sb+u0],__ATOMIC_RELAXED,__HIP_MEMORY_SCOPE_AGENT);
          if ((v>>16)==tag) break;
          __builtin_amdgcn_s_sleep(1);
        }
        unsigned short pv=(unsigned short)(v&0xffffu);
        _Float16 hv; __builtin_memcpy(&hv,&pv,2);
        hls[u0]=hv;
        if (fi<38){
          int f1=fi+214;            // foreign index 214..251
          int u1=(f1<own_lo)? f1 : f1+42;
          for(;;){
            v=__hip_atomic_load(&HX[sb+u1],__ATOMIC_RELAXED,__HIP_MEMORY_SCOPE_AGENT);
            if ((v>>16)==tag) break;
            __builtin_amdgcn_s_sleep(1);
          }
          pv=(unsigned short)(v&0xffffu);
          __builtin_memcpy(&hv,&pv,2);
          hls[u1]=hv;
        }
      }
      __syncthreads();
    }
  }
}

// ---------- GAT layer 1: split-row masked softmax + rank-2 aggregation (320 thr) ----------
__global__ void k10_gat1(float* ws) {
  int bid=blockIdx.x; int m=bid>>2, k=bid&3; int tid=threadIdx.x; // 320 thr
  __shared__ float x0[147],x1[147],f1[147],f2[147];
  __shared__ float sp[294], a0p[294], a1p[294];
  __shared__ unsigned long long msk[441];
  for (int i=tid;i<294;i+=320){
    int n=i>>1,cc=i&1;
    float v=ws[Y3o + (size_t)n*1536 + m*2 + cc];
    if(cc==0)x0[n]=v; else x1[n]=v;
  }
  const unsigned long long* gm = (const unsigned long long*)(ws+MASKo);
  for (int i=tid;i<441;i+=320) msk[i]=gm[i];
  __syncthreads();
  float c10=ws[C12o+k*2], c11=ws[C12o+k*2+1], c20=ws[C12o+8+k*2], c21=ws[C12o+8+k*2+1];
  for (int i=tid;i<147;i+=320){ f1[i]=x0[i]*c10+x1[i]*c11; f2[i]=x0[i]*c20+x1[i]*c21; }
  __syncthreads();
  if (tid<294){
    int i=tid>>1, hf=tid&1;
    int j0=hf?74:0, j1=hf?147:74;
    float fi=f1[i];
    float s=0.f,a0=0.f,a1=0.f;
    for (int j=j0;j<j1;++j){
      bool mk=(msk[i*3+(j>>6)]>>(j&63))&1ull;
      float e=fi+f2[j];
      e=fmaxf(e,0.f)+0.1f*fminf(e,0.f);
      e=fminf(e,80.f);
      float pv=mk? __expf(e):0.f;
      s+=pv; a0+=pv*x0[j]; a1+=pv*x1[j];
    }
    sp[tid]=s; a0p[tid]=a0; a1p[tid]=a1;
  }
  __syncthreads();
  if (tid<147){
    float inv=1.f/(sp[2*tid]+sp[2*tid+1]);
    size_t o = So + ((size_t)(m*4+k)*147+tid)*2;
    ws[o]=(a0p[2*tid]+a0p[2*tid+1])*inv;
    ws[o+1]=(a1p[2*tid]+a1p[2*tid+1])*inv;
  }
}

// ---------- GAT layer 2 GEMM (MFMA, 512 thr / 8 waves): whoT = (elu(h1)@W2)^T ----------
__global__ void __launch_bounds__(512) k11_who(const float* gw1, float* ws) {
  int m=blockIdx.x, tid=threadIdx.x;
  int w=tid>>6, l=tid&63, lr=l&15, kg=l>>4;
  int wc=w&3, rbase=(w>>2)*5;
  __shared__ float s0s[4][148], s1s[4][148];
  __shared__ float w1s[1024];
  __shared__ _Float16 h1t[160*72];
  for (int idx=tid; idx<588; idx+=512){
    int k=idx/147, i=idx-k*147;
    size_t o=So+((size_t)(m*4+k)*147+i)*2; s0s[k][i]=ws[o]; s1s[k][i]=ws[o+1];
  }
  for (int idx=tid; idx<1024; idx+=512) w1s[idx]=gw1[idx];
  f32x4 acc[5][2];
  #pragma unroll
  for(int a=0;a<5;++a){ acc[a][0]=(f32x4){0.f,0.f,0.f,0.f}; acc[a][1]=(f32x4){0.f,0.f,0.f,0.f}; }
  const _Float16* W2T = (const _Float16*)(ws+W2To);
  for (int q0=0;q0<512;q0+=64){
    __syncthreads();
    for (int idx=tid; idx<10240; idx+=512){
      int i=idx>>6, c=idx&63;
      _Float16 hv=(_Float16)0.f;
      if (i<147){
        int q=q0+c, k=q>>7, hp=q&127;
        float v=s0s[k][i]*w1s[k*256+hp]+s1s[k][i]*w1s[k*256+128+hp];
        hv=(_Float16)eluf(v);
      }
      h1t[i*72+c]=hv;
    }
    __syncthreads();
    #pragma unroll
    for (int ks2=0; ks2<2; ++ks2){
      int qq=q0+ks2*32;
      half8 bv0=*(const half8*)(W2T+(size_t)(wc*32+lr)*512+qq+kg*8);
      half8 bv1=*(const half8*)(W2T+(size_t)(wc*32+16+lr)*512+qq+kg*8);
      #pragma unroll
      for (int rf2=0;rf2<5;++rf2){
        half8 av=*(const half8*)&h1t[((rbase+rf2)*16+lr)*72 + ks2*32 + kg*8];
        acc[rf2][0]=__builtin_amdgcn_mfma_f32_16x16x32_f16(av,bv0,acc[rf2][0],0,0,0);
        acc[rf2][1]=__builtin_amdgcn_mfma_f32_16x16x32_f16(av,bv1,acc[rf2][1],0,0,0);
      }
    }
  }
  _Float16* whoT=(_Float16*)(ws+WHOTo);
  #pragma unroll
  for (int rf2=0;rf2<5;++rf2)
    #pragma unroll
    for (int cf=0;cf<2;++cf){
      int col=wc*32+cf*16+lr;
      half4 hv = {(_Float16)acc[rf2][cf][0],(_Float16)acc[rf2][cf][1],
                  (_Float16)acc[rf2][cf][2],(_Float16)acc[rf2][cf][3]};
      *(half4*)&whoT[((size_t)m*128+col)*160 + (rbase+rf2)*16+kg*4] = hv;
    }
}

// ---------- GAT layer 2 (512 thr): split g12 + split softmax + 8-wave MFMA PV ----------
__global__ void __launch_bounds__(512) k13_gat2(const float* X, const float* Wsc, const float* bsc,
                                               const float* ga2, float* ws) {
  int m=blockIdx.x, tid=threadIdx.x; // 512 thr, 8 waves
  int w=tid>>6, l=tid&63, lr=l&15, kg=l>>4;
  int wc=w&3, rbase=(w>>2)*5;
  __shared__ _Float16 att_h[160*172];
  __shared__ float g1s[160], g2s[160];
  __shared__ float sre[160];
  __shared__ float g1h[320], g2h[320], sp[294];
  __shared__ float a2s[256];
  __shared__ float wscs[256], bscs[128];
  __shared__ unsigned long long msk[441];
  _Float16* zf=(_Float16*)(ws+Zo);
  const _Float16* whoT=(const _Float16*)(ws+WHOTo);
  if (tid<256){ wscs[tid]=Wsc[tid]; a2s[tid]=ga2[tid]; }
  if (tid<128) bscs[tid]=bsc[tid];
  const unsigned long long* gm=(const unsigned long long*)(ws+MASKo);
  for (int i=tid;i<441;i+=512) msk[i]=gm[i];
  __syncthreads();
  // phase 0: g1/g2 split over (row, half) = 320 tasks of 64 iters
  if (tid<320){
    int row=tid>>1, hf=tid&1;
    float g1=0.f,g2=0.f;
    for (int h=hf*64;h<hf*64+64;++h){
      float v=(float)whoT[((size_t)m*128+h)*160+row];
      g1+=v*a2s[h]; g2+=v*a2s[128+h];
    }
    g1h[tid]=g1; g2h[tid]=g2;
  }
  __syncthreads();
  if (tid<160){ g1s[tid]=g1h[2*tid]+g1h[2*tid+1]; g2s[tid]=g2h[2*tid]+g2h[2*tid+1]; }
  // zero-fill att_h padding
  for (int idx=tid; idx<2080; idx+=512){ int r=idx/13, jx=147+(idx-(idx/13)*13); att_h[r*172+jx]=(_Float16)0.f; }
  for (int idx=tid; idx<1911; idx+=512){ int r=147+idx/147, jx=idx-(idx/147)*147; att_h[r*172+jx]=(_Float16)0.f; }
  __syncthreads();
  // phase 1: softmax split over (row, half), unnormalized fp16
  if (tid<294){
    int row=tid>>1, hf=tid&1;
    int j0=hf?74:0, j1=hf?147:74;
    float gi=g1s[row];
    float s=0.f;
    for (int j=j0;j<j1;++j){
      bool mk=(msk[row*3+(j>>6)]>>(j&63))&1ull;
      float e=gi+g2s[j];
      e=fmaxf(e,0.f)+0.1f*fminf(e,0.f);
      e=fminf(e,11.f);
      float pv=mk? __expf(e):0.f;
      att_h[row*172+j]=(_Float16)pv;
      s+=pv;
    }
    sp[tid]=s;
  }
  __syncthreads();
  if (tid<147) sre[tid]=1.f/(sp[2*tid]+sp[2*tid+1]);
  __syncthreads();
  // phase 2: PV via MFMA, 8 waves
  f32x4 acc[5][2];
  #pragma unroll
  for (int a=0;a<5;++a){ acc[a][0]=(f32x4){0.f,0.f,0.f,0.f}; acc[a][1]=(f32x4){0.f,0.f,0.f,0.f}; }
  int c0=wc*32+lr, c1=wc*32+16+lr;
  #pragma unroll
  for (int s=0;s<5;++s){
    int j0=s*32;
    half8 bv0=*(const half8*)&whoT[((size_t)m*128+c0)*160+j0+kg*8];
    half8 bv1=*(const half8*)&whoT[((size_t)m*128+c1)*160+j0+kg*8];
    #pragma unroll
    for (int rf2=0;rf2<5;++rf2){
      half8 av=*(const half8*)&att_h[((rbase+rf2)*16+lr)*172+j0+kg*8];
      acc[rf2][0]=__builtin_amdgcn_mfma_f32_16x16x32_f16(av,bv0,acc[rf2][0],0,0,0);
      acc[rf2][1]=__builtin_amdgcn_mfma_f32_16x16x32_f16(av,bv1,acc[rf2][1],0,0,0);
    }
  }
  // phase 3: epilogue (deferred normalization)
  #pragma unroll
  for (int rf2=0;rf2<5;++rf2)
    #pragma unroll
    for (int r_=0;r_<4;++r_){
      int row=(rbase+rf2)*16+kg*4+r_;
      if (row<147){
        float inv=sre[row];
        int gbase=row*98304+m*128;
        int bs=gbase/903168; int r2=gbase-bs*903168;
        int t=r2/18816; int qb=r2-t*18816;
        int nn=qb>>7;
        const float* xr=X+(size_t)(bs*48+t)*294+nn*2;
        float x0=xr[0],x1=xr[1];
        size_t zb=(size_t)(bs*48+t)*18816+qb;
        #pragma unroll
        for (int cf=0;cf<2;++cf){
          int col=wc*32+cf*16+lr;
          float pv=acc[rf2][cf][r_]*inv;
          float sv=x0*wscs[col*2]+x1*wscs[col*2+1]+bscs[col];
          zf[zb+col]=(_Float16)(eluf(pv)+eluf(sv));
        }
      }
    }
}

// ---------- Zg = Zf @ WfT : block-tiled LDS MFMA GEMM, 256x256 tiles, split-K=12 ----------
__global__ void __launch_bounds__(512) k14_tile(float* ws) {
  int tid=threadIdx.x;
  int wave=tid>>6, l=tid&63, lr=l&15, kg=l>>4;
  int wm=wave>>2, wn=wave&3;
  int m0=blockIdx.x*256, n0=blockIdx.y*256, ks=blockIdx.z;
  const _Float16* A=(const _Float16*)(ws+Zo);   // [768][18816]
  const _Float16* B=(const _Float16*)(ws+WFo);  // [512][18816]
  __shared__ _Float16 As[2][256*40];
  __shared__ _Float16 Bs[2][256*40];
  f32x4 acc[8][4];
  #pragma unroll
  for (int a=0;a<8;++a)
    #pragma unroll
    for (int b=0;b<4;++b) acc[a][b]=(f32x4){0.f,0.f,0.f,0.f};
  int kbase=ks*1568;
  int row=tid>>2, seg=tid&3;
  {
    int kb=kbase;
    *(half8*)&As[0][(size_t)row*40+seg*8]       = *(const half8*)(A+(size_t)(m0+row)*18816+kb+seg*8);
    *(half8*)&As[0][(size_t)(row+128)*40+seg*8] = *(const half8*)(A+(size_t)(m0+row+128)*18816+kb+seg*8);
    *(half8*)&Bs[0][(size_t)row*40+seg*8]       = *(const half8*)(B+(size_t)(n0+row)*18816+kb+seg*8);
    *(half8*)&Bs[0][(size_t)(row+128)*40+seg*8] = *(const half8*)(B+(size_t)(n0+row+128)*18816+kb+seg*8);
  }
  __syncthreads();
  for (int c=0;c<49;++c){
    int cur=c&1, nxt=cur^1;
    if (c<48){
      int kb=kbase+(c+1)*32;
      *(half8*)&As[nxt][(size_t)row*40+seg*8]       = *(const half8*)(A+(size_t)(m0+row)*18816+kb+seg*8);
      *(half8*)&As[nxt][(size_t)(row+128)*40+seg*8] = *(const half8*)(A+(size_t)(m0+row+128)*18816+kb+seg*8);
      *(half8*)&Bs[nxt][(size_t)row*40+seg*8]       = *(const half8*)(B+(size_t)(n0+row)*18816+kb+seg*8);
      *(half8*)&Bs[nxt][(size_t)(row+128)*40+seg*8] = *(const half8*)(B+(size_t)(n0+row+128)*18816+kb+seg*8);
    }
    half8 bfr[4], afr[8];
    #pragma unroll
    for (int fn=0;fn<4;++fn) bfr[fn]=*(const half8*)&Bs[cur][(size_t)(wn*64+fn*16+lr)*40+kg*8];
    #pragma unroll
    for (int fm=0;fm<8;++fm) afr[fm]=*(const half8*)&As[cur][(size_t)(wm*128+fm*16+lr)*40+kg*8];
    #pragma unroll
    for (int fm=0;fm<8;++fm)
      #pragma unroll
      for (int fn=0;fn<4;++fn)
        acc[fm][fn]=__builtin_amdgcn_mfma_f32_16x16x32_f16(afr[fm],bfr[fn],acc[fm][fn],0,0,0);
    __syncthreads();
  }
  float* P = ws + ZGPo + (size_t)ks*393216;
  #pragma unroll
  for (int fm=0;fm<8;++fm)
    #pragma unroll
    for (int fn=0;fn<4;++fn)
      #pragma unroll
      for (int r=0;r<4;++r)
        P[(size_t)(m0+wm*128+fm*16+kg*4+r)*512 + n0+wn*64+fn*16+lr] = acc[fm][fn][r];
}

// ---------- split-K reduce + biases ----------
__global__ void k14b_red(const float* bih2, const float* bhh2, float* ws) {
  int i = blockIdx.x*256+threadIdx.x;
  int g = i & 511;
  float s = bih2[g]+bhh2[g];
  #pragma unroll
  for (int ks=0;ks<12;++ks) s += ws[ZGPo + (size_t)ks*393216 + i];
  ws[ZGo + i] = s;
}

// ---------- LSTM2 recurrence + fused final FC (4-acc ILP) ----------
__global__ void __launch_bounds__(512) k15_lstm2(const float* Wfc, const float* bfc, float* out, float* ws) {
  int b=blockIdx.x, tid=threadIdx.x; // 512 thr
  __shared__ __align__(16) _Float16 wl[65536];
  __shared__ __align__(16) _Float16 hs[128];
  __shared__ float cc[128], g[512];
  const half8* wsrc=(const half8*)(ws+WT2Ho);
  for (int i=tid;i<8192;i+=512) ((half8*)wl)[i]=wsrc[i];
  if (tid<128){hs[tid]=(_Float16)0.f; cc[tid]=0.f;}
  __syncthreads();
  for (int t=0;t<48;++t){
    int row=b*48+t;
    float a0=ws[ZGo+(size_t)row*512+tid], a1=0.f, a2=0.f, a3=0.f;
    #pragma unroll
    for (int gi=0;gi<16;gi+=4){
      half8 w0=*(const half8*)&wl[((size_t)gi*512+tid)*8];
      half8 w1=*(const half8*)&wl[((size_t)(gi+1)*512+tid)*8];
      half8 w2=*(const half8*)&wl[((size_t)(gi+2)*512+tid)*8];
      half8 w3=*(const half8*)&wl[((size_t)(gi+3)*512+tid)*8];
      const half2v* h0=(const half2v*)&hs[gi*8];
      const half2v* h1=(const half2v*)&hs[(gi+1)*8];
      const half2v* h2=(const half2v*)&hs[(gi+2)*8];
      const half2v* h3=(const half2v*)&hs[(gi+3)*8];
      #pragma unroll
      for (int q=0;q<4;++q){
        half2v wp0={w0[2*q],w0[2*q+1]}; a0=DOT2(wp0,h0[q],a0);
        half2v wp1={w1[2*q],w1[2*q+1]}; a1=DOT2(wp1,h1[q],a1);
        half2v wp2={w2[2*q],w2[2*q+1]}; a2=DOT2(wp2,h2[q],a2);
        half2v wp3={w3[2*q],w3[2*q+1]}; a3=DOT2(wp3,h3[q],a3);
      }
    }
    g[tid]=(a0+a1)+(a2+a3);
    __syncthreads();
    if (tid<128){
      float ii=sigf(g[tid]);
      float ff=sigf(g[128+tid]);
      float gg=tanhf(g[256+tid]);
      float oo=sigf(g[384+tid]);
      float cn=ff*cc[tid]+ii*gg; cc[tid]=cn;
      float hn=oo*tanhf(cn);
      hs[tid]=(_Float16)hn;
    }
    __syncthreads();
  }
  // fused FC from LDS-resident final h
  if (tid<294){
    float acc=bfc[tid];
    const float* wr=Wfc+tid*128;
    for (int k=0;k<128;++k) acc+=(float)hs[k]*wr[k];
    out[b*294+tid]=acc;
  }
}

extern "C" void kernel_launch(void* const* d_in, const int* in_sizes, int n_in,
                              void* d_out, int out_size, void* d_ws, size_t ws_size,
                              hipStream_t stream) {
  const float* X    =(const float*)d_in[0];
  const int*   adj  =(const int*)  d_in[1];
  const float* Wtr  =(const float*)d_in[2];
  const float* btr  =(const float*)d_in[3];
  const float* einw =(const float*)d_in[4];
  const float* einb =(const float*)d_in[5];
  const float* eoutw=(const float*)d_in[6];
  const float* eoutb=(const float*)d_in[7];
  const float* ln1g =(const float*)d_in[8];
  const float* ln1b =(const float*)d_in[9];
  const float* ln2g =(const float*)d_in[10];
  const float* ln2b =(const float*)d_in[11];
  const float* ff1w =(const float*)d_in[12];
  const float* ff1b =(const float*)d_in[13];
  const float* ff2w =(const float*)d_in[14];
  const float* ff2b =(const float*)d_in[15];
  const float* Wih1 =(const float*)d_in[16];
  const float* Whh1 =(const float*)d_in[17];
  const float* bih1 =(const float*)d_in[18];
  const float* bhh1 =(const float*)d_in[19];
  const float* gw1  =(const float*)d_in[20];
  const float* ga1  =(const float*)d_in[21];
  const float* gw2  =(const float*)d_in[22];
  const float* ga2  =(const float*)d_in[23];
  const float* Wsc  =(const float*)d_in[24];
  const float* bsc  =(const float*)d_in[25];
  const float* Wih2 =(const float*)d_in[26];
  const float* Whh2 =(const float*)d_in[27];
  const float* bih2 =(const float*)d_in[28];
  const float* bhh2 =(const float*)d_in[29];
  const float* Wfc  =(const float*)d_in[30];
  const float* bfc  =(const float*)d_in[31];
  float* ws=(float*)d_ws;
  float* out=(float*)d_out;

  k_prep_all<<<dim3(14340),dim3(256),0,stream>>>(Whh1,Whh2,ff1w,ff2w,Wih1,einw,eoutw,Wtr,gw2,
                                                 Wih2,gw1,ga1,adj,ws);
  k1_qkv<<<dim3(768),dim3(384),0,stream>>>(X,btr,einb,ws);
  k3_attn<<<dim3(256),dim3(256),0,stream>>>(ws);
  k4_ln1<<<dim3(768),dim3(128),0,stream>>>(eoutb,ln1g,ln1b,ws);
  k5g<<<dim3(384),dim3(64),0,stream>>>(ff1b,ws);
  k6g<<<dim3(96),dim3(64),0,stream>>>(ws);
  k6b_ln2<<<dim3(768),dim3(128),0,stream>>>(ff2b,ln2g,ln2b,ws);
  k7g<<<dim3(228),dim3(64),0,stream>>>(bih1,bhh1,ws);
  k8_lstm1<<<dim3(112),dim3(256),0,stream>>>(ws);
  k10_gat1<<<dim3(3072),dim3(320),0,stream>>>(ws);
  k11_who<<<dim3(768),dim3(512),0,stream>>>(gw1,ws);
  k13_gat2<<<dim3(768),dim3(512),0,stream>>>(X,Wsc,bsc,ga2,ws);
  k14_tile<<<dim3(3,2,12),dim3(512),0,stream>>>(ws);
  k14b_red<<<dim3(1536),dim3(256),0,stream>>>(bih2,bhh2,ws);
  k15_lstm2<<<dim3(16),dim3(512),0,stream>>>(Wfc,bfc,out,ws);
}

// Round 20
// 459.715 us; speedup vs baseline: 1.0256x; 1.0256x over previous
//
#include <hip/hip_runtime.h>
#include <math.h>

// ---- problem sizes ----
// BS=16, T=48, N=147, IN=294, H=128, AH=8(dh=16), GH=4, DFF=2048, B2=BS*T=768

typedef _Float16 half8 __attribute__((ext_vector_type(8)));
typedef _Float16 half4 __attribute__((ext_vector_type(4)));
typedef _Float16 half2v __attribute__((ext_vector_type(2)));
typedef float f32x4 __attribute__((ext_vector_type(4)));

#if __has_builtin(__builtin_amdgcn_fdot2)
#define DOT2(a,b,c) __builtin_amdgcn_fdot2((a),(b),(c),false)
#else
#define DOT2(a,b,c) ((c) + (float)(a)[0]*(float)(b)[0] + (float)(a)[1]*(float)(b)[1])
#endif

// ---- workspace float offsets ----
static constexpr size_t Y0o   = 0;         //  98304  [768][128] f32
static constexpr size_t QKVo  = 98304;     // 294912  [768][384] f32
static constexpr size_t ATTOo = 393216;    //  98304
static constexpr size_t Y1o   = 491520;    //  98304  f32 (residual for k6b)
static constexpr size_t Y1Ho  = 589824;    //  49152  fp16 [768][128]
static constexpr size_t FFHo  = 638976;    // 786432  fp16 [768][2048]
static constexpr size_t Y2Ho  = 1523712;   //  49152  fp16 [768][128]
static constexpr size_t XW1o  = 1572864;   // 903168  f32 [768][1176]
static constexpr size_t Y3o   = 2476032;   // 225792  f32 [768][294] (ends 2701824)
static constexpr size_t Zo    = 0;         // fp16 [768][18816] = 7225344 floats (aliases phase A)
static constexpr size_t So    = 7225344;   // 903168  [768][4][147][2]
static constexpr size_t WHOTo = 8354304;   // fp16 [768][128][160] = 7864320 floats (ends 16218624)
static constexpr size_t WFo   = 16218624;  // fp16 [512][18816] = 4816896 (ends 21035520)
static constexpr size_t ZGPo  = 21035520;  // f32 [12][768][512] = 4718592 (also k6g partials early)
static constexpr size_t ZGo   = 25754112;  // 393216 [768][512]
static constexpr size_t HTo   = 26147328;  //   2048 [16][128]
static constexpr size_t C12o  = 26149376;  //     16
static constexpr size_t WT1Ho = 26149392;  // fp16 [7 p][37 kg][168 row][8] = 348096 -> 174048 floats
static constexpr size_t WT2Ho = 26323440;  // fp16 [16][512][8]  = 32768
static constexpr size_t FF1Ho = 26356208;  // fp16 [2048][128] = 131072
static constexpr size_t FF2Ho = 26487280;  // fp16 [128][2048] = 131072
static constexpr size_t WIH1Ho= 26618352;  // fp16 [1216][128] = 77824 (rows>=1176 zero)
static constexpr size_t W2To  = 26696176;  // fp16 [128][512] = 32768
static constexpr size_t EINTo = 26728944;  //  49152 [128][384] f32
static constexpr size_t EOUTTo= 26778096;  //  16384 [128][128] f32
static constexpr size_t WTRTo = 26794480;  //  37632 [294][128] f32
static constexpr size_t MASKo = 26832112;  //  u64[441] (896 floats reserved)
static constexpr size_t HXo   = 26833008;  //  u32[2][16][294] = 9408 u32 = 9408 floats
// total extent: 26,842,416 floats = 102.4 MiB

__device__ __forceinline__ float eluf(float x){ return x > 0.f ? x : __expf(x)-1.f; }
__device__ __forceinline__ float sigf(float x){ return 1.f/(1.f+__expf(-x)); }

// ---------- merged: weight transposes / fp16 packs + Wih2 conv + c12/mask/HX ----------
__global__ void k_prep_all(const float* Whh1, const float* Whh2, const float* ff1w,
                           const float* ff2w, const float* Wih1, const float* einw,
                           const float* eoutw, const float* wtr, const float* gw2,
                           const float* Wih2, const float* gw1, const float* ga1,
                           const int* adj, float* ws) {
  int bb = blockIdx.x;
  int tid = threadIdx.x;
  if (bb < 4931) {
    int id = bb * 256 + tid;
    if (id < 348096) { // WT1S fp16 [7 p][37 kg][168 row][8 e]
      int e=id&7, r=id>>3; int row=r%168; int q=r/168; int kg=q%37; int p=q/37;
      int k=kg*8+e; int gate=row/42, jr=row-gate*42; int j=gate*294+p*42+jr;
      ((_Float16*)(ws+WT1Ho))[id] = (_Float16)((k<294)? Whh1[j*294+k] : 0.f); return; }
    id -= 348096;
    if (id < 65536) { // WT2H fp16 [16][512][8]
      int e=id&7, r=id>>3; int j=r&511, gi=r>>9; int k=gi*8+e;
      ((_Float16*)(ws+WT2Ho))[id] = (_Float16)Whh2[j*128+k]; return; }
    id -= 65536;
    if (id < 262144) { ((_Float16*)(ws+FF1Ho))[id] = (_Float16)ff1w[id]; return; }
    id -= 262144;
    if (id < 262144) { ((_Float16*)(ws+FF2Ho))[id] = (_Float16)ff2w[id]; return; }
    id -= 262144;
    if (id < 155648) { int j=id>>7, k=id&127;
      ((_Float16*)(ws+WIH1Ho))[id] = (_Float16)((j<1176)? Wih1[j*128+k] : 0.f); return; }
    id -= 155648;
    if (id < 65536)  { int h=id>>9, q=id&511;
      ((_Float16*)(ws+W2To))[id] = (_Float16)gw2[q*128+h]; return; }
    id -= 65536;
    if (id < 49152)  { int k=id/384,  j=id-k*384;  ws[EINTo+id] = einw[j*128+k]; return; }
    id -= 49152;
    if (id < 16384)  { int k=id/128,  j=id-k*128;  ws[EOUTTo+id]= eoutw[j*128+k]; return; }
    id -= 16384;
    if (id < 37632)  { int k=id/128,  j=id-k*128;  ws[WTRTo+id] = wtr[j*294+k]; return; }
    return;
  }
  if (bb < 14339) { // Wih2 -> fp16
    size_t i = ((size_t)(bb-4931)*256 + tid)*4;
    _Float16* wf = (_Float16*)(ws + WFo);
    float4 v = *(const float4*)&Wih2[i];
    half4 h = {(_Float16)v.x, (_Float16)v.y, (_Float16)v.z, (_Float16)v.w};
    *(half4*)&wf[i] = h;
    return;
  }
  // last block: c12 + adjacency bitmask + HX reset
  if (tid < 8) {
    int k = tid>>1, c = tid&1;
    float a=0.f, b=0.f;
    for (int h=0; h<128; ++h) {
      float w = gw1[(k*2+c)*128+h];
      a += w * ga1[k*256+h];
      b += w * ga1[k*256+128+h];
    }
    ws[C12o+tid] = a; ws[C12o+8+tid] = b;
  }
  unsigned long long* msk = (unsigned long long*)(ws + MASKo);
  for (int i = tid; i < 441; i += 256) {
    int r = i/3, w = i-r*3;
    unsigned long long b = 0ull;
    for (int bit=0; bit<64; ++bit) {
      int j = w*64+bit;
      if (j < 147 && adj[r*147+j] > 0) b |= (1ull<<bit);
    }
    msk[i] = b;
  }
  unsigned* hx = (unsigned*)(ws + HXo);
  for (int i=tid;i<9408;i+=256) hx[i]=0u;
}

// ---------- fused input projection + ELU + QKV ----------
__global__ void k1_qkv(const float* X, const float* btr, const float* einb, float* ws) {
  int row = blockIdx.x, tid = threadIdx.x; // 384 thr
  __shared__ float xr[294];
  __shared__ float yr[128];
  for (int i=tid; i<294; i+=384) xr[i] = X[row*294+i];
  __syncthreads();
  if (tid<128){
    float acc = btr[tid];
    const float* w = ws + WTRTo;
    for (int k=0;k<294;++k) acc += xr[k]*w[k*128+tid];
    float v = eluf(acc);
    yr[tid]=v;
    ws[Y0o + (size_t)row*128 + tid] = v;
  }
  __syncthreads();
  float acc = einb[tid];
  const float* w = ws + EINTo;
  for (int k=0;k<128;++k) acc += yr[k]*w[k*384+tid];
  ws[QKVo + (size_t)row*384 + tid] = acc;
}

// ---------- MHA core: one block per (bs, head, row-half) = 256 blocks ----------
__global__ void k3_attn(float* ws) {
  int bid = blockIdx.x; int bs = bid>>4; int a=(bid>>1)&7; int hf=bid&1; int tid = threadIdx.x; // 256 thr
  __shared__ float q[24][16], kk[48][16], v[48][16], sc[24][49];
  int r0=hf*24;
  for (int idx=tid; idx<768; idx+=256) {
    int t = idx>>4, d = idx&15;
    const float* base = ws + QKVo + (size_t)(bs*48+t)*384 + a*16 + d;
    kk[t][d] = base[128]; v[t][d] = base[256];
  }
  for (int idx=tid; idx<384; idx+=256) {
    int t = idx>>4, d = idx&15;
    q[t][d] = ws[QKVo + (size_t)(bs*48+r0+t)*384 + a*16 + d];
  }
  __syncthreads();
  for (int idx=tid; idx<1152; idx+=256) {
    int i = idx/48, j = idx-i*48;
    float s = 0.f;
    for (int d=0;d<16;++d) s += q[i][d]*kk[j][d];
    sc[i][j] = s*0.25f;
  }
  __syncthreads();
  if (tid < 24) {
    float mx = -INFINITY;
    for (int j=0;j<48;++j) mx = fmaxf(mx, sc[tid][j]);
    float s = 0.f;
    for (int j=0;j<48;++j){ float p = __expf(sc[tid][j]-mx); sc[tid][j]=p; s+=p; }
    float inv = 1.f/s;
    for (int j=0;j<48;++j) sc[tid][j]*=inv;
  }
  __syncthreads();
  for (int idx=tid; idx<384; idx+=256) {
    int t = idx>>4, d = idx&15;
    float s=0.f;
    for (int j=0;j<48;++j) s += sc[t][j]*v[j][d];
    ws[ATTOo + (size_t)(bs*48+r0+t)*128 + a*16 + d] = s;
  }
}

// ---------- attn out-proj + residual + LN1 (stores f32 + fp16) ----------
__global__ void k4_ln1(const float* eoutb, const float* g, const float* b, float* ws) {
  int row = blockIdx.x, tid = threadIdx.x; // 128 thr
  __shared__ float orow[128];
  __shared__ float red[128];
  __shared__ float mv[2];
  orow[tid] = ws[ATTOo+(size_t)row*128+tid];
  __syncthreads();
  float acc = eoutb[tid] + ws[Y0o+(size_t)row*128+tid];
  const float* w = ws + EOUTTo;
  for (int k=0;k<128;++k) acc += orow[k]*w[k*128+tid];
  red[tid]=acc; __syncthreads();
  for (int s=64;s>0;s>>=1){ if(tid<s) red[tid]+=red[tid+s]; __syncthreads(); }
  if (tid==0) mv[0]=red[0]*(1.f/128.f);
  __syncthreads();
  float d = acc - mv[0];
  red[tid]=d*d; __syncthreads();
  for (int s=64;s>0;s>>=1){ if(tid<s) red[tid]+=red[tid+s]; __syncthreads(); }
  if (tid==0) mv[1]=red[0]*(1.f/128.f);
  __syncthreads();
  float val = d*rsqrtf(mv[1]+1e-5f)*g[tid]+b[tid];
  ws[Y1o+(size_t)row*128+tid] = val;
  ((_Float16*)(ws+Y1Ho))[(size_t)row*128+tid] = (_Float16)val;
}

// ---------- FFN1 MFMA (1 wave/block, 384 blocks): FFH = relu(Y1 @ ff1w^T + b1), fp16 out ----------
__global__ void __launch_bounds__(64) k5g(const float* b1, float* ws) {
  int tid=threadIdx.x; int gw=blockIdx.x;
  int l=tid&63, lr=l&15, kg=l>>4;
  int mt=gw>>5, nt=gw&31;
  const _Float16* A=(const _Float16*)(ws+Y1Ho);
  const _Float16* B=(const _Float16*)(ws+FF1Ho);
  _Float16* C=(_Float16*)(ws+FFHo);
  size_t r0=(size_t)mt*64, c0=(size_t)nt*64;
  f32x4 acc[4][4];
  #pragma unroll
  for(int a=0;a<4;++a)
    #pragma unroll
    for(int b=0;b<4;++b) acc[a][b]=(f32x4){0.f,0.f,0.f,0.f};
  #pragma unroll
  for (int s=0;s<4;++s){
    int kb=s*32+kg*8;
    half8 av[4], bv[4];
    #pragma unroll
    for(int f=0;f<4;++f) av[f]=*(const half8*)(A+(r0+f*16+lr)*128+kb);
    #pragma unroll
    for(int f=0;f<4;++f) bv[f]=*(const half8*)(B+(c0+f*16+lr)*128+kb);
    #pragma unroll
    for(int fr=0;fr<4;++fr)
      #pragma unroll
      for(int fc=0;fc<4;++fc)
        acc[fr][fc]=__builtin_amdgcn_mfma_f32_16x16x32_f16(av[fr],bv[fc],acc[fr][fc],0,0,0);
  }
  #pragma unroll
  for(int fr=0;fr<4;++fr)
    #pragma unroll
    for(int fc=0;fc<4;++fc){
      size_t col=c0+fc*16+lr;
      float bb=b1[col];
      #pragma unroll
      for(int r=0;r<4;++r){
        float v=acc[fr][fc][r]+bb; v=fmaxf(v,0.f);
        C[(r0+fr*16+kg*4+r)*2048+col]=(_Float16)v;
      }
    }
}

// ---------- FFN2 MFMA split-K=4 (1 wave/block, 96 blocks): ZGP[ksp] partials ----------
__global__ void __launch_bounds__(64) k6g(float* ws) {
  int tid=threadIdx.x; int gw=blockIdx.x;
  int l=tid&63, lr=l&15, kg=l>>4;
  int ksp=gw&3, nt=(gw>>2)&1, mt=gw>>3;
  const _Float16* A=(const _Float16*)(ws+FFHo);
  const _Float16* B=(const _Float16*)(ws+FF2Ho);
  float* C=ws+ZGPo+(size_t)ksp*98304;
  size_t r0=(size_t)mt*64, c0=(size_t)nt*64;
  f32x4 acc[4][4];
  #pragma unroll
  for(int a=0;a<4;++a)
    #pragma unroll
    for(int b=0;b<4;++b) acc[a][b]=(f32x4){0.f,0.f,0.f,0.f};
  #pragma unroll
  for (int s=0;s<16;++s){
    int kb=ksp*512+s*32+kg*8;
    half8 av[4], bv[4];
    #pragma unroll
    for(int f=0;f<4;++f) av[f]=*(const half8*)(A+(r0+f*16+lr)*2048+kb);
    #pragma unroll
    for(int f=0;f<4;++f) bv[f]=*(const half8*)(B+(c0+f*16+lr)*2048+kb);
    #pragma unroll
    for(int fr=0;fr<4;++fr)
      #pragma unroll
      for(int fc=0;fc<4;++fc)
        acc[fr][fc]=__builtin_amdgcn_mfma_f32_16x16x32_f16(av[fr],bv[fc],acc[fr][fc],0,0,0);
  }
  #pragma unroll
  for(int fr=0;fr<4;++fr)
    #pragma unroll
    for(int fc=0;fc<4;++fc){
      size_t col=c0+fc*16+lr;
      #pragma unroll
      for(int r=0;r<4;++r)
        C[(r0+fr*16+kg*4+r)*128+col]=acc[fr][fc][r];
    }
}

// ---------- LN2: Y2H = LN(Y1 + b2 + sum ZGP partials) fp16 ----------
__global__ void k6b_ln2(const float* b2, const float* g, const float* b, float* ws) {
  int row=blockIdx.x, tid=threadIdx.x; // 128 thr
  __shared__ float red[128];
  __shared__ float mv[2];
  float acc = ws[Y1o+(size_t)row*128+tid] + b2[tid];
  #pragma unroll
  for (int ksp=0;ksp<4;++ksp) acc += ws[ZGPo+(size_t)ksp*98304+(size_t)row*128+tid];
  red[tid]=acc; __syncthreads();
  for (int s=64;s>0;s>>=1){ if(tid<s) red[tid]+=red[tid+s]; __syncthreads(); }
  if (tid==0) mv[0]=red[0]*(1.f/128.f);
  __syncthreads();
  float d = acc - mv[0];
  red[tid]=d*d; __syncthreads();
  for (int s=64;s>0;s>>=1){ if(tid<s) red[tid]+=red[tid+s]; __syncthreads(); }
  if (tid==0) mv[1]=red[0]*(1.f/128.f);
  __syncthreads();
  float val = d*rsqrtf(mv[1]+1e-5f)*g[tid]+b[tid];
  ((_Float16*)(ws+Y2Ho))[(size_t)row*128+tid] = (_Float16)val;
}

// ---------- LSTM1 input proj MFMA (1 wave/block, 228 blocks): XW1 = Y2 @ Wih1^T + biases ----------
__global__ void __launch_bounds__(64) k7g(const float* bih1, const float* bhh1, float* ws) {
  int tid=threadIdx.x; int gw=blockIdx.x;
  int l=tid&63, lr=l&15, kg=l>>4;
  int mt=gw/19, nt=gw-mt*19;
  const _Float16* A=(const _Float16*)(ws+Y2Ho);
  const _Float16* B=(const _Float16*)(ws+WIH1Ho);
  float* C=ws+XW1o;
  size_t r0=(size_t)mt*64, c0=(size_t)nt*64;
  f32x4 acc[4][4];
  #pragma unroll
  for(int a=0;a<4;++a)
    #pragma unroll
    for(int b=0;b<4;++b) acc[a][b]=(f32x4){0.f,0.f,0.f,0.f};
  #pragma unroll
  for (int s=0;s<4;++s){
    int kb=s*32+kg*8;
    half8 av[4], bv[4];
    #pragma unroll
    for(int f=0;f<4;++f) av[f]=*(const half8*)(A+(r0+f*16+lr)*128+kb);
    #pragma unroll
    for(int f=0;f<4;++f) bv[f]=*(const half8*)(B+(c0+f*16+lr)*128+kb);
    #pragma unroll
    for(int fr=0;fr<4;++fr)
      #pragma unroll
      for(int fc=0;fc<4;++fc)
        acc[fr][fc]=__builtin_amdgcn_mfma_f32_16x16x32_f16(av[fr],bv[fc],acc[fr][fc],0,0,0);
  }
  #pragma unroll
  for(int fr=0;fr<4;++fr)
    #pragma unroll
    for(int fc=0;fc<4;++fc){
      size_t col=c0+fc*16+lr;
      if (col<1176){
        float bb=bih1[col]+bhh1[col];
        #pragma unroll
        for(int r=0;r<4;++r)
          C[(r0+fr*16+kg*4+r)*1176+col]=acc[fr][fc][r]+bb;
      }
    }
}

// ---------- LSTM1 recurrence: 7 blocks/batch, LDS weights, u32 seqlock (2-acc, r18 proven) ----------
__global__ void __launch_bounds__(256) k8_lstm1(float* ws) {
  int blk=blockIdx.x; int xcd=blk&7; int slot7=blk>>3;
  int b=xcd+8*(slot7/7), p=slot7%7; int tid=threadIdx.x; // 112 blocks, 256 thr
  __shared__ __align__(16) _Float16 wl[49728];  // [37 kg][168 row][8] = 97KB
  __shared__ __align__(16) _Float16 hls[296];
  __shared__ float gbuf[168];
  __shared__ float cloc[42];
  const half8* wsrc = (const half8*)((const _Float16*)(ws+WT1Ho) + (size_t)p*49728);
  for (int i=tid;i<6216;i+=256) ((half8*)wl)[i]=wsrc[i];
  if (tid<42) cloc[tid]=0.f;
  for (int i=tid;i<296;i+=256) hls[i]=(_Float16)0.f;
  unsigned* HX=(unsigned*)(ws+HXo); // [2][16][294] u32
  int gate=tid/42, jr=tid-gate*42;  // meaningful for tid<168
  int j=(tid<168)? gate*294+p*42+jr : 0;
  float xw = (tid<168)? ws[XW1o+(size_t)(b*48)*1176+j] : 0.f;
  int own_lo=p*42;
  __syncthreads();
  for (int t=0;t<48;++t){
    if (tid<168){
      float a0=xw, a1=0.f;
      #pragma unroll
      for (int gi=0;gi<36;gi+=2){
        half8 w0=*(const half8*)&wl[((size_t)gi*168+tid)*8];
        half8 w1=*(const half8*)&wl[((size_t)(gi+1)*168+tid)*8];
        const half2v* h0=(const half2v*)&hls[gi*8];
        const half2v* h1=(const half2v*)&hls[(gi+1)*8];
        #pragma unroll
        for (int q=0;q<4;++q){
          half2v wp0={w0[2*q],w0[2*q+1]}; a0=DOT2(wp0,h0[q],a0);
          half2v wp1={w1[2*q],w1[2*q+1]}; a1=DOT2(wp1,h1[q],a1);
        }
      }
      {
        half8 w0=*(const half8*)&wl[((size_t)36*168+tid)*8];
        const half2v* h0=(const half2v*)&hls[36*8];
        #pragma unroll
        for (int q=0;q<4;++q){ half2v wp0={w0[2*q],w0[2*q+1]}; a0=DOT2(wp0,h0[q],a0); }
      }
      gbuf[tid]=a0+a1;
    }
    __syncthreads();
    if (tid<42){
      int k=p*42+tid;
      float ii=sigf(gbuf[tid]);
      float ff=sigf(gbuf[42+tid]);
      float gg=tanhf(gbuf[84+tid]);
      float oo=sigf(gbuf[126+tid]);
      float cn=ff*cloc[tid]+ii*gg; cloc[tid]=cn;
      float hn=oo*tanhf(cn);
      _Float16 hh=(_Float16)hn;
      hls[k]=hh;
      if (t<47){
        unsigned short pb; __builtin_memcpy(&pb,&hh,2);
        unsigned v=(((unsigned)(t+1))<<16)|(unsigned)pb;
        __hip_atomic_store(&HX[(unsigned)(((t+1)&1)*4704 + b*294 + k)], v,
                           __ATOMIC_RELAXED, __HIP_MEMORY_SCOPE_AGENT);
      }
      ws[Y3o+(size_t)(b*48+t)*294+k]=hn;
    }
    if (t<47){
      if (tid<168) xw = ws[XW1o+(size_t)(b*48+t+1)*1176+j]; // prefetch hides under poll
      unsigned tag=(unsigned)(t+1);
      unsigned sb=(unsigned)(((t+1)&1)*4704 + b*294);
      if (tid>=42){
        int fi = tid-42;            // foreign index 0..213
        int u0 = (fi<own_lo)? fi : fi+42;
        unsigned v;
        for(;;){
          v=__hip_atomic_load(&HX[sb+u0],__ATOMIC_RELAXED,__HIP_MEMORY_SCOPE_AGENT);
          if ((v>>16)==tag) break;
          __builtin_amdgcn_s_sleep(1);
        }
        unsigned short pv=(unsigned short)(v&0xffffu);
        _Float16 hv; __builtin_memcpy(&hv,&pv,2);
        hls[u0]=hv;
        if (fi<38){
          int f1=fi+214;            // foreign index 214..251
          int u1=(f1<own_lo)? f1 : f1+42;
          for(;;){
            v=__hip_atomic_load(&HX[sb+u1],__ATOMIC_RELAXED,__HIP_MEMORY_SCOPE_AGENT);
            if ((v>>16)==tag) break;
            __builtin_amdgcn_s_sleep(1);
          }
          pv=(unsigned short)(v&0xffffu);
          __builtin_memcpy(&hv,&pv,2);
          hls[u1]=hv;
        }
      }
      __syncthreads();
    }
  }
}

// ---------- GAT layer 1: split-row masked softmax + rank-2 aggregation (320 thr) ----------
__global__ void k10_gat1(float* ws) {
  int bid=blockIdx.x; int m=bid>>2, k=bid&3; int tid=threadIdx.x; // 320 thr
  __shared__ float x0[147],x1[147],f1[147],f2[147];
  __shared__ float sp[294], a0p[294], a1p[294];
  __shared__ unsigned long long msk[441];
  for (int i=tid;i<294;i+=320){
    int n=i>>1,cc=i&1;
    float v=ws[Y3o + (size_t)n*1536 + m*2 + cc];
    if(cc==0)x0[n]=v; else x1[n]=v;
  }
  const unsigned long long* gm = (const unsigned long long*)(ws+MASKo);
  for (int i=tid;i<441;i+=320) msk[i]=gm[i];
  __syncthreads();
  float c10=ws[C12o+k*2], c11=ws[C12o+k*2+1], c20=ws[C12o+8+k*2], c21=ws[C12o+8+k*2+1];
  for (int i=tid;i<147;i+=320){ f1[i]=x0[i]*c10+x1[i]*c11; f2[i]=x0[i]*c20+x1[i]*c21; }
  __syncthreads();
  if (tid<294){
    int i=tid>>1, hf=tid&1;
    int j0=hf?74:0, j1=hf?147:74;
    float fi=f1[i];
    float s=0.f,a0=0.f,a1=0.f;
    for (int j=j0;j<j1;++j){
      bool mk=(msk[i*3+(j>>6)]>>(j&63))&1ull;
      float e=fi+f2[j];
      e=fmaxf(e,0.f)+0.1f*fminf(e,0.f);
      e=fminf(e,80.f);
      float pv=mk? __expf(e):0.f;
      s+=pv; a0+=pv*x0[j]; a1+=pv*x1[j];
    }
    sp[tid]=s; a0p[tid]=a0; a1p[tid]=a1;
  }
  __syncthreads();
  if (tid<147){
    float inv=1.f/(sp[2*tid]+sp[2*tid+1]);
    size_t o = So + ((size_t)(m*4+k)*147+tid)*2;
    ws[o]=(a0p[2*tid]+a0p[2*tid+1])*inv;
    ws[o+1]=(a1p[2*tid]+a1p[2*tid+1])*inv;
  }
}

// ---------- GAT layer 2 GEMM (MFMA, 512 thr / 8 waves): whoT = (elu(h1)@W2)^T ----------
__global__ void __launch_bounds__(512) k11_who(const float* gw1, float* ws) {
  int m=blockIdx.x, tid=threadIdx.x;
  int w=tid>>6, l=tid&63, lr=l&15, kg=l>>4;
  int wc=w&3, rbase=(w>>2)*5;
  __shared__ float s0s[4][148], s1s[4][148];
  __shared__ float w1s[1024];
  __shared__ _Float16 h1t[160*72];
  for (int idx=tid; idx<588; idx+=512){
    int k=idx/147, i=idx-k*147;
    size_t o=So+((size_t)(m*4+k)*147+i)*2; s0s[k][i]=ws[o]; s1s[k][i]=ws[o+1];
  }
  for (int idx=tid; idx<1024; idx+=512) w1s[idx]=gw1[idx];
  f32x4 acc[5][2];
  #pragma unroll
  for(int a=0;a<5;++a){ acc[a][0]=(f32x4){0.f,0.f,0.f,0.f}; acc[a][1]=(f32x4){0.f,0.f,0.f,0.f}; }
  const _Float16* W2T = (const _Float16*)(ws+W2To);
  for (int q0=0;q0<512;q0+=64){
    __syncthreads();
    for (int idx=tid; idx<10240; idx+=512){
      int i=idx>>6, c=idx&63;
      _Float16 hv=(_Float16)0.f;
      if (i<147){
        int q=q0+c, k=q>>7, hp=q&127;
        float v=s0s[k][i]*w1s[k*256+hp]+s1s[k][i]*w1s[k*256+128+hp];
        hv=(_Float16)eluf(v);
      }
      h1t[i*72+c]=hv;
    }
    __syncthreads();
    #pragma unroll
    for (int ks2=0; ks2<2; ++ks2){
      int qq=q0+ks2*32;
      half8 bv0=*(const half8*)(W2T+(size_t)(wc*32+lr)*512+qq+kg*8);
      half8 bv1=*(const half8*)(W2T+(size_t)(wc*32+16+lr)*512+qq+kg*8);
      #pragma unroll
      for (int rf2=0;rf2<5;++rf2){
        half8 av=*(const half8*)&h1t[((rbase+rf2)*16+lr)*72 + ks2*32 + kg*8];
        acc[rf2][0]=__builtin_amdgcn_mfma_f32_16x16x32_f16(av,bv0,acc[rf2][0],0,0,0);
        acc[rf2][1]=__builtin_amdgcn_mfma_f32_16x16x32_f16(av,bv1,acc[rf2][1],0,0,0);
      }
    }
  }
  _Float16* whoT=(_Float16*)(ws+WHOTo);
  #pragma unroll
  for (int rf2=0;rf2<5;++rf2)
    #pragma unroll
    for (int cf=0;cf<2;++cf){
      int col=wc*32+cf*16+lr;
      half4 hv = {(_Float16)acc[rf2][cf][0],(_Float16)acc[rf2][cf][1],
                  (_Float16)acc[rf2][cf][2],(_Float16)acc[rf2][cf][3]};
      *(half4*)&whoT[((size_t)m*128+col)*160 + (rbase+rf2)*16+kg*4] = hv;
    }
}

// ---------- GAT layer 2 (512 thr): split g12 + split softmax + 8-wave MFMA PV ----------
__global__ void __launch_bounds__(512) k13_gat2(const float* X, const float* Wsc, const float* bsc,
                                               const float* ga2, float* ws) {
  int m=blockIdx.x, tid=threadIdx.x; // 512 thr, 8 waves
  int w=tid>>6, l=tid&63, lr=l&15, kg=l>>4;
  int wc=w&3, rbase=(w>>2)*5;
  __shared__ _Float16 att_h[160*172];
  __shared__ float g1s[160], g2s[160];
  __shared__ float sre[160];
  __shared__ float g1h[320], g2h[320], sp[294];
  __shared__ float a2s[256];
  __shared__ float wscs[256], bscs[128];
  __shared__ unsigned long long msk[441];
  _Float16* zf=(_Float16*)(ws+Zo);
  const _Float16* whoT=(const _Float16*)(ws+WHOTo);
  if (tid<256){ wscs[tid]=Wsc[tid]; a2s[tid]=ga2[tid]; }
  if (tid<128) bscs[tid]=bsc[tid];
  const unsigned long long* gm=(const unsigned long long*)(ws+MASKo);
  for (int i=tid;i<441;i+=512) msk[i]=gm[i];
  __syncthreads();
  if (tid<320){
    int row=tid>>1, hf=tid&1;
    float g1=0.f,g2=0.f;
    for (int h=hf*64;h<hf*64+64;++h){
      float v=(float)whoT[((size_t)m*128+h)*160+row];
      g1+=v*a2s[h]; g2+=v*a2s[128+h];
    }
    g1h[tid]=g1; g2h[tid]=g2;
  }
  __syncthreads();
  if (tid<160){ g1s[tid]=g1h[2*tid]+g1h[2*tid+1]; g2s[tid]=g2h[2*tid]+g2h[2*tid+1]; }
  for (int idx=tid; idx<2080; idx+=512){ int r=idx/13, jx=147+(idx-(idx/13)*13); att_h[r*172+jx]=(_Float16)0.f; }
  for (int idx=tid; idx<1911; idx+=512){ int r=147+idx/147, jx=idx-(idx/147)*147; att_h[r*172+jx]=(_Float16)0.f; }
  __syncthreads();
  if (tid<294){
    int row=tid>>1, hf=tid&1;
    int j0=hf?74:0, j1=hf?147:74;
    float gi=g1s[row];
    float s=0.f;
    for (int j=j0;j<j1;++j){
      bool mk=(msk[row*3+(j>>6)]>>(j&63))&1ull;
      float e=gi+g2s[j];
      e=fmaxf(e,0.f)+0.1f*fminf(e,0.f);
      e=fminf(e,11.f);
      float pv=mk? __expf(e):0.f;
      att_h[row*172+j]=(_Float16)pv;
      s+=pv;
    }
    sp[tid]=s;
  }
  __syncthreads();
  if (tid<147) sre[tid]=1.f/(sp[2*tid]+sp[2*tid+1]);
  __syncthreads();
  f32x4 acc[5][2];
  #pragma unroll
  for (int a=0;a<5;++a){ acc[a][0]=(f32x4){0.f,0.f,0.f,0.f}; acc[a][1]=(f32x4){0.f,0.f,0.f,0.f}; }
  int c0=wc*32+lr, c1=wc*32+16+lr;
  #pragma unroll
  for (int s=0;s<5;++s){
    int j0=s*32;
    half8 bv0=*(const half8*)&whoT[((size_t)m*128+c0)*160+j0+kg*8];
    half8 bv1=*(const half8*)&whoT[((size_t)m*128+c1)*160+j0+kg*8];
    #pragma unroll
    for (int rf2=0;rf2<5;++rf2){
      half8 av=*(const half8*)&att_h[((rbase+rf2)*16+lr)*172+j0+kg*8];
      acc[rf2][0]=__builtin_amdgcn_mfma_f32_16x16x32_f16(av,bv0,acc[rf2][0],0,0,0);
      acc[rf2][1]=__builtin_amdgcn_mfma_f32_16x16x32_f16(av,bv1,acc[rf2][1],0,0,0);
    }
  }
  #pragma unroll
  for (int rf2=0;rf2<5;++rf2)
    #pragma unroll
    for (int r_=0;r_<4;++r_){
      int row=(rbase+rf2)*16+kg*4+r_;
      if (row<147){
        float inv=sre[row];
        int gbase=row*98304+m*128;
        int bs=gbase/903168; int r2=gbase-bs*903168;
        int t=r2/18816; int qb=r2-t*18816;
        int nn=qb>>7;
        const float* xr=X+(size_t)(bs*48+t)*294+nn*2;
        float x0=xr[0],x1=xr[1];
        size_t zb=(size_t)(bs*48+t)*18816+qb;
        #pragma unroll
        for (int cf=0;cf<2;++cf){
          int col=wc*32+cf*16+lr;
          float pv=acc[rf2][cf][r_]*inv;
          float sv=x0*wscs[col*2]+x1*wscs[col*2+1]+bscs[col];
          zf[zb+col]=(_Float16)(eluf(pv)+eluf(sv));
        }
      }
    }
}

// ---------- Zg = Zf @ WfT : block-tiled LDS MFMA GEMM, 256x256 tiles, split-K=12 ----------
__global__ void __launch_bounds__(512) k14_tile(float* ws) {
  int tid=threadIdx.x;
  int wave=tid>>6, l=tid&63, lr=l&15, kg=l>>4;
  int wm=wave>>2, wn=wave&3;
  int m0=blockIdx.x*256, n0=blockIdx.y*256, ks=blockIdx.z;
  const _Float16* A=(const _Float16*)(ws+Zo);   // [768][18816]
  const _Float16* B=(const _Float16*)(ws+WFo);  // [512][18816]
  __shared__ _Float16 As[2][256*40];
  __shared__ _Float16 Bs[2][256*40];
  f32x4 acc[8][4];
  #pragma unroll
  for (int a=0;a<8;++a)
    #pragma unroll
    for (int b=0;b<4;++b) acc[a][b]=(f32x4){0.f,0.f,0.f,0.f};
  int kbase=ks*1568;
  int row=tid>>2, seg=tid&3;
  {
    int kb=kbase;
    *(half8*)&As[0][(size_t)row*40+seg*8]       = *(const half8*)(A+(size_t)(m0+row)*18816+kb+seg*8);
    *(half8*)&As[0][(size_t)(row+128)*40+seg*8] = *(const half8*)(A+(size_t)(m0+row+128)*18816+kb+seg*8);
    *(half8*)&Bs[0][(size_t)row*40+seg*8]       = *(const half8*)(B+(size_t)(n0+row)*18816+kb+seg*8);
    *(half8*)&Bs[0][(size_t)(row+128)*40+seg*8] = *(const half8*)(B+(size_t)(n0+row+128)*18816+kb+seg*8);
  }
  __syncthreads();
  for (int c=0;c<49;++c){
    int cur=c&1, nxt=cur^1;
    if (c<48){
      int kb=kbase+(c+1)*32;
      *(half8*)&As[nxt][(size_t)row*40+seg*8]       = *(const half8*)(A+(size_t)(m0+row)*18816+kb+seg*8);
      *(half8*)&As[nxt][(size_t)(row+128)*40+seg*8] = *(const half8*)(A+(size_t)(m0+row+128)*18816+kb+seg*8);
      *(half8*)&Bs[nxt][(size_t)row*40+seg*8]       = *(const half8*)(B+(size_t)(n0+row)*18816+kb+seg*8);
      *(half8*)&Bs[nxt][(size_t)(row+128)*40+seg*8] = *(const half8*)(B+(size_t)(n0+row+128)*18816+kb+seg*8);
    }
    half8 bfr[4], afr[8];
    #pragma unroll
    for (int fn=0;fn<4;++fn) bfr[fn]=*(const half8*)&Bs[cur][(size_t)(wn*64+fn*16+lr)*40+kg*8];
    #pragma unroll
    for (int fm=0;fm<8;++fm) afr[fm]=*(const half8*)&As[cur][(size_t)(wm*128+fm*16+lr)*40+kg*8];
    #pragma unroll
    for (int fm=0;fm<8;++fm)
      #pragma unroll
      for (int fn=0;fn<4;++fn)
        acc[fm][fn]=__builtin_amdgcn_mfma_f32_16x16x32_f16(afr[fm],bfr[fn],acc[fm][fn],0,0,0);
    __syncthreads();
  }
  float* P = ws + ZGPo + (size_t)ks*393216;
  #pragma unroll
  for (int fm=0;fm<8;++fm)
    #pragma unroll
    for (int fn=0;fn<4;++fn)
      #pragma unroll
      for (int r=0;r<4;++r)
        P[(size_t)(m0+wm*128+fm*16+kg*4+r)*512 + n0+wn*64+fn*16+lr] = acc[fm][fn][r];
}

// ---------- split-K reduce + biases ----------
__global__ void k14b_red(const float* bih2, const float* bhh2, float* ws) {
  int i = blockIdx.x*256+threadIdx.x;
  int g = i & 511;
  float s = bih2[g]+bhh2[g];
  #pragma unroll
  for (int ks=0;ks<12;++ks) s += ws[ZGPo + (size_t)ks*393216 + i];
  ws[ZGo + i] = s;
}

// ---------- LSTM2 recurrence + fused final FC (2-acc, r18 proven) ----------
__global__ void __launch_bounds__(512) k15_lstm2(const float* Wfc, const float* bfc, float* out, float* ws) {
  int b=blockIdx.x, tid=threadIdx.x; // 512 thr
  __shared__ __align__(16) _Float16 wl[65536];
  __shared__ __align__(16) _Float16 hs[128];
  __shared__ float cc[128], g[512];
  const half8* wsrc=(const half8*)(ws+WT2Ho);
  for (int i=tid;i<8192;i+=512) ((half8*)wl)[i]=wsrc[i];
  if (tid<128){hs[tid]=(_Float16)0.f; cc[tid]=0.f;}
  __syncthreads();
  for (int t=0;t<48;++t){
    int row=b*48+t;
    float a0=ws[ZGo+(size_t)row*512+tid], a1=0.f;
    #pragma unroll
    for (int gi=0;gi<16;gi+=2){
      half8 w0=*(const half8*)&wl[((size_t)gi*512+tid)*8];
      half8 w1=*(const half8*)&wl[((size_t)(gi+1)*512+tid)*8];
      const half2v* h0=(const half2v*)&hs[gi*8];
      const half2v* h1=(const half2v*)&hs[(gi+1)*8];
      #pragma unroll
      for (int q=0;q<4;++q){
        half2v wp0={w0[2*q],w0[2*q+1]}; a0=DOT2(wp0,h0[q],a0);
        half2v wp1={w1[2*q],w1[2*q+1]}; a1=DOT2(wp1,h1[q],a1);
      }
    }
    g[tid]=a0+a1;
    __syncthreads();
    if (tid<128){
      float ii=sigf(g[tid]);
      float ff=sigf(g[128+tid]);
      float gg=tanhf(g[256+tid]);
      float oo=sigf(g[384+tid]);
      float cn=ff*cc[tid]+ii*gg; cc[tid]=cn;
      float hn=oo*tanhf(cn);
      hs[tid]=(_Float16)hn;
    }
    __syncthreads();
  }
  // fused FC from LDS-resident final h
  if (tid<294){
    float acc=bfc[tid];
    const float* wr=Wfc+tid*128;
    for (int k=0;k<128;++k) acc+=(float)hs[k]*wr[k];
    out[b*294+tid]=acc;
  }
}

extern "C" void kernel_launch(void* const* d_in, const int* in_sizes, int n_in,
                              void* d_out, int out_size, void* d_ws, size_t ws_size,
                              hipStream_t stream) {
  const float* X    =(const float*)d_in[0];
  const int*   adj  =(const int*)  d_in[1];
  const float* Wtr  =(const float*)d_in[2];
  const float* btr  =(const float*)d_in[3];
  const float* einw =(const float*)d_in[4];
  const float* einb =(const float*)d_in[5];
  const float* eoutw=(const float*)d_in[6];
  const float* eoutb=(const float*)d_in[7];
  const float* ln1g =(const float*)d_in[8];
  const float* ln1b =(const float*)d_in[9];
  const float* ln2g =(const float*)d_in[10];
  const float* ln2b =(const float*)d_in[11];
  const float* ff1w =(const float*)d_in[12];
  const float* ff1b =(const float*)d_in[13];
  const float* ff2w =(const float*)d_in[14];
  const float* ff2b =(const float*)d_in[15];
  const float* Wih1 =(const float*)d_in[16];
  const float* Whh1 =(const float*)d_in[17];
  const float* bih1 =(const float*)d_in[18];
  const float* bhh1 =(const float*)d_in[19];
  const float* gw1  =(const float*)d_in[20];
  const float* ga1  =(const float*)d_in[21];
  const float* gw2  =(const float*)d_in[22];
  const float* ga2  =(const float*)d_in[23];
  const float* Wsc  =(const float*)d_in[24];
  const float* bsc  =(const float*)d_in[25];
  const float* Wih2 =(const float*)d_in[26];
  const float* Whh2 =(const float*)d_in[27];
  const float* bih2 =(const float*)d_in[28];
  const float* bhh2 =(const float*)d_in[29];
  const float* Wfc  =(const float*)d_in[30];
  const float* bfc  =(const float*)d_in[31];
  float* ws=(float*)d_ws;
  float* out=(float*)d_out;

  k_prep_all<<<dim3(14340),dim3(256),0,stream>>>(Whh1,Whh2,ff1w,ff2w,Wih1,einw,eoutw,Wtr,gw2,
                                                 Wih2,gw1,ga1,adj,ws);
  k1_qkv<<<dim3(768),dim3(384),0,stream>>>(X,btr,einb,ws);
  k3_attn<<<dim3(256),dim3(256),0,stream>>>(ws);
  k4_ln1<<<dim3(768),dim3(128),0,stream>>>(eoutb,ln1g,ln1b,ws);
  k5g<<<dim3(384),dim3(64),0,stream>>>(ff1b,ws);
  k6g<<<dim3(96),dim3(64),0,stream>>>(ws);
  k6b_ln2<<<dim3(768),dim3(128),0,stream>>>(ff2b,ln2g,ln2b,ws);
  k7g<<<dim3(228),dim3(64),0,stream>>>(bih1,bhh1,ws);
  k8_lstm1<<<dim3(112),dim3(256),0,stream>>>(ws);
  k10_gat1<<<dim3(3072),dim3(320),0,stream>>>(ws);
  k11_who<<<dim3(768),dim3(512),0,stream>>>(gw1,ws);
  k13_gat2<<<dim3(768),dim3(512),0,stream>>>(X,Wsc,bsc,ga2,ws);
  k14_tile<<<dim3(3,2,12),dim3(512),0,stream>>>(ws);
  k14b_red<<<dim3(1536),dim3(256),0,stream>>>(bih2,bhh2,ws);
  k15_lstm2<<<dim3(16),dim3(512),0,stream>>>(Wfc,bfc,out,ws);
}